// Round 6
// baseline (409.118 us; speedup 1.0000x reference)
//
#include <hip/hip_runtime.h>
#include <math.h>

// Problem sizes (fixed)
#define BB 8
#define NC_ 384
#define NG 6
#define GC_ 64
#define NH 12
#define HC_ 32
#define NQ 1024
#define NPOS_ELEMS (BB*NQ*NC_)       // 3,145,728
#define WT_ELEMS (NG*9*GC_*GC_)      // 221,184 per conv split plane
#define WSQ (NC_*NC_)                // 147,456 per square-weight plane

typedef short bf16x8 __attribute__((ext_vector_type(8)));
typedef float f32x4  __attribute__((ext_vector_type(4)));

__device__ inline ushort f2bf(float f) {
    union { float f; unsigned u; } v; v.f = f;
    unsigned r = v.u + 0x7FFFu + ((v.u >> 16) & 1u);   // RNE
    return (ushort)(r >> 16);
}
__device__ inline float bf2f(ushort h) {
    union { unsigned u; float f; } v; v.u = ((unsigned)h) << 16;
    return v.f;
}
__device__ inline bf16x8 pack8(const float* f) {
    bf16x8 r;
#pragma unroll
    for (int i = 0; i < 8; ++i) r[i] = (short)f2bf(f[i]);
    return r;
}

// =====================================================================
// fp32 -> hi/lo bf16 split (hi at [0,n), lo at [n,2n)).
// =====================================================================
__global__ __launch_bounds__(256) void split_k(
    const float* __restrict__ in, ushort* __restrict__ out, int n)
{
    const int i = (blockIdx.x * 256 + threadIdx.x) * 4;
    float4 v = *(const float4*)&in[i];
    ushort4 hi, lo;
    hi.x = f2bf(v.x); lo.x = f2bf(v.x - bf2f(hi.x));
    hi.y = f2bf(v.y); lo.y = f2bf(v.y - bf2f(hi.y));
    hi.z = f2bf(v.z); lo.z = f2bf(v.z - bf2f(hi.z));
    hi.w = f2bf(v.w); lo.w = f2bf(v.w - bf2f(hi.w));
    *(ushort4*)&out[i] = hi;
    *(ushort4*)&out[n + i] = lo;
}

// =====================================================================
// Square weight transpose + split: W[k][n] fp32 -> wt[mat][plane][n][k] bf16.
// =====================================================================
__global__ __launch_bounds__(256) void wsplit_k(
    const float* __restrict__ w0, const float* __restrict__ w1,
    const float* __restrict__ w2, const float* __restrict__ w3,
    ushort* __restrict__ wt)
{
    const int mat = blockIdx.z;
    const float* W = mat == 0 ? w0 : mat == 1 ? w1 : mat == 2 ? w2 : w3;
    const int kt0 = blockIdx.x * 64, nt0 = blockIdx.y * 64;
    __shared__ float Ts[64][68];
    const int tid = threadIdx.x;
    {
        const int kl = tid >> 4, nl = (tid & 15) * 4;
#pragma unroll
        for (int rr = 0; rr < 4; ++rr)
            *(float4*)&Ts[kl + rr * 16][nl] =
                *(const float4*)&W[(size_t)(kt0 + kl + rr * 16) * NC_ + nt0 + nl];
    }
    __syncthreads();
    {
        const int n = tid >> 2, k0 = (tid & 3) * 16;
        ushort* dst = &wt[(size_t)mat * 2 * WSQ + (size_t)(nt0 + n) * NC_ + kt0 + k0];
#pragma unroll
        for (int j8 = 0; j8 < 16; j8 += 8) {
            bf16x8 hi8, lo8;
#pragma unroll
            for (int j = 0; j < 8; ++j) {
                float f = Ts[k0 + j8 + j][n];
                ushort h = f2bf(f);
                hi8[j] = (short)h;
                lo8[j] = (short)f2bf(f - bf2f(h));
            }
            *(bf16x8*)&dst[j8] = hi8;
            *(bf16x8*)&dst[WSQ + j8] = lo8;
        }
    }
}

// =====================================================================
// Barrier-free global-only split-bf16 MFMA GEMM: C = A @ W + bias.
// Ahl = [hi][lo] bf16 [M][384]; Wt = [plane][n][k] bf16.
// Block = 64 rows x 64 cols, 4 waves x 16 rows. All fragments straight
// from global (L1/L2-resident), no LDS, no __syncthreads.
// =====================================================================
template<int OUT_BF16>
__global__ __launch_bounds__(256) void gemm_gl_k(
    const ushort* __restrict__ Ahl, const ushort* __restrict__ Wt,
    const float* __restrict__ bias, void* __restrict__ Cv, int M)
{
    const size_t alo = (size_t)M * NC_;
    const int m0 = blockIdx.x * 64;
    const int n0 = blockIdx.y * 64;
    const int tid = threadIdx.x;
    const int w = tid >> 6;
    const int lane = tid & 63;
    const int c15 = lane & 15;
    const int lg = lane >> 4;

    f32x4 acc[4];
#pragma unroll
    for (int ct = 0; ct < 4; ++ct) acc[ct] = (f32x4){0.f, 0.f, 0.f, 0.f};

    const ushort* arow = &Ahl[(size_t)(m0 + w * 16 + c15) * NC_ + lg * 8];
    const ushort* brow = &Wt[(size_t)(n0 + c15) * NC_ + lg * 8];

#pragma unroll 2
    for (int ks = 0; ks < NC_; ks += 32) {
        bf16x8 Ah = *(const bf16x8*)(arow + ks);
        bf16x8 Al = *(const bf16x8*)(arow + alo + ks);
#pragma unroll
        for (int ct = 0; ct < 4; ++ct) {
            bf16x8 Bh = *(const bf16x8*)(brow + (size_t)ct * 16 * NC_ + ks);
            bf16x8 Bl = *(const bf16x8*)(brow + WSQ + (size_t)ct * 16 * NC_ + ks);
            acc[ct] = __builtin_amdgcn_mfma_f32_16x16x32_bf16(Ah, Bh, acc[ct], 0, 0, 0);
            acc[ct] = __builtin_amdgcn_mfma_f32_16x16x32_bf16(Al, Bh, acc[ct], 0, 0, 0);
            acc[ct] = __builtin_amdgcn_mfma_f32_16x16x32_bf16(Ah, Bl, acc[ct], 0, 0, 0);
        }
    }

#pragma unroll
    for (int ct = 0; ct < 4; ++ct) {
        const int col = n0 + ct * 16 + c15;
        const float bv = bias[col];
#pragma unroll
        for (int r = 0; r < 4; ++r) {
            const size_t row = m0 + w * 16 + lg * 4 + r;
            const float val = acc[ct][r] + bv;
            if constexpr (OUT_BF16)
                ((ushort*)Cv)[row * NC_ + col] = f2bf(val);
            else
                ((float*)Cv)[row * NC_ + col] = val;
        }
    }
}

// =====================================================================
// Conv weight transpose + split (unchanged, validated).
// =====================================================================
__global__ __launch_bounds__(256) void wconv_t_k(
    const float* __restrict__ w, ushort* __restrict__ wt)
{
    const int i = blockIdx.x * 256 + threadIdx.x;
    const int g = i / (9 * GC_ * GC_);
    const int rem = i % (9 * GC_ * GC_);
    const int tap = rem / (GC_ * GC_);
    const int rem2 = rem % (GC_ * GC_);
    const int oc = rem2 >> 6;
    const int ic = rem2 & 63;
    float v = w[(size_t)(tap * GC_ + ic) * NC_ + g * GC_ + oc];
    ushort hi = f2bf(v);
    ushort lo = f2bf(v - bf2f(hi));
    wt[i] = hi;
    wt[WT_ELEMS + i] = lo;
}

// =====================================================================
// Grouped 3x3 conv as split-bf16 implicit-GEMM MFMA (unchanged, validated).
// =====================================================================
__global__ __launch_bounds__(256) void conv_mfma_k(
    const float* __restrict__ q, const ushort* __restrict__ wt,
    const float* __restrict__ bias, float* __restrict__ t)
{
    const int bid = blockIdx.x;
    const int g = bid % NG;
    const int rg = (bid / NG) & 7;
    const int b = bid / (NG * 8);
    const int y0 = rg * 4;

    __shared__ __align__(16) ushort At[2][6 * 34 * 64];

    const int tid = threadIdx.x;
    const int wv = tid >> 6;
    const int lane = tid & 63;
    const int c15 = lane & 15;
    const int lg = lane >> 4;
    const int oc = wv * 16 + c15;

    for (int idx = tid; idx < 6 * 34 * 8; idx += 256) {
        const int cell = idx >> 3;
        const int ch0 = (idx & 7) << 3;
        const int rr = cell / 34, cc = cell % 34;
        const int yy = y0 + rr - 1, xx = cc - 1;
        float v[8];
        if ((unsigned)yy < 32u && (unsigned)xx < 32u) {
            const float* src = &q[(size_t)((b * 32 + yy) * 32 + xx) * NC_ + g * GC_ + ch0];
            *(float4*)&v[0] = *(const float4*)src;
            *(float4*)&v[4] = *(const float4*)(src + 4);
        } else {
#pragma unroll
            for (int j = 0; j < 8; ++j) v[j] = 0.f;
        }
        bf16x8 hi8, lo8;
#pragma unroll
        for (int j = 0; j < 8; ++j) {
            ushort h = f2bf(v[j]);
            hi8[j] = (short)h;
            lo8[j] = (short)f2bf(v[j] - bf2f(h));
        }
        const int wi = cell * 64 + (ch0 ^ ((cc & 7) << 3));
        *(bf16x8*)&At[0][wi] = hi8;
        *(bf16x8*)&At[1][wi] = lo8;
    }

    const float bval = bias[g * GC_ + oc];
    f32x4 acc[8];
#pragma unroll
    for (int m = 0; m < 8; ++m) acc[m] = (f32x4){bval, bval, bval, bval};

    __syncthreads();

#pragma unroll
    for (int tap = 0; tap < 9; ++tap) {
        const int kh = tap / 3, kw = tap % 3;
        const ushort* wb = &wt[(size_t)((g * 9 + tap) * GC_ + oc) * GC_ + lg * 8];
        bf16x8 Bh0 = *(const bf16x8*)&wb[0];
        bf16x8 Bh1 = *(const bf16x8*)&wb[32];
        bf16x8 Bl0 = *(const bf16x8*)&wb[WT_ELEMS];
        bf16x8 Bl1 = *(const bf16x8*)&wb[WT_ELEMS + 32];
#pragma unroll
        for (int m = 0; m < 8; ++m) {
            const int rr = (m >> 1) + kh;
            const int cc = (m & 1) * 16 + kw + c15;
            const int base = (rr * 34 + cc) * 64;
            const int sw = (cc & 7) << 3;
            bf16x8 Ah0 = *(const bf16x8*)&At[0][base + ((lg * 8) ^ sw)];
            bf16x8 Ah1 = *(const bf16x8*)&At[0][base + ((32 + lg * 8) ^ sw)];
            bf16x8 Al0 = *(const bf16x8*)&At[1][base + ((lg * 8) ^ sw)];
            bf16x8 Al1 = *(const bf16x8*)&At[1][base + ((32 + lg * 8) ^ sw)];
            acc[m] = __builtin_amdgcn_mfma_f32_16x16x32_bf16(Ah0, Bh0, acc[m], 0, 0, 0);
            acc[m] = __builtin_amdgcn_mfma_f32_16x16x32_bf16(Ah1, Bh1, acc[m], 0, 0, 0);
            acc[m] = __builtin_amdgcn_mfma_f32_16x16x32_bf16(Al0, Bh0, acc[m], 0, 0, 0);
            acc[m] = __builtin_amdgcn_mfma_f32_16x16x32_bf16(Al1, Bh1, acc[m], 0, 0, 0);
            acc[m] = __builtin_amdgcn_mfma_f32_16x16x32_bf16(Ah0, Bl0, acc[m], 0, 0, 0);
            acc[m] = __builtin_amdgcn_mfma_f32_16x16x32_bf16(Ah1, Bl1, acc[m], 0, 0, 0);
        }
    }

#pragma unroll
    for (int m = 0; m < 8; ++m) {
        const int y = y0 + (m >> 1);
#pragma unroll
        for (int r = 0; r < 4; ++r) {
            const int x = (m & 1) * 16 + lg * 4 + r;
            t[(size_t)((b * 32 + y) * 32 + x) * NC_ + g * GC_ + oc] = acc[m][r];
        }
    }
}

// =====================================================================
// LayerNorm(384) + erf-GELU + per-group 64->2 proj + tanh*16 + ref grid.
// =====================================================================
__global__ __launch_bounds__(384) void ln_gelu_off_k(
    const float* __restrict__ t, const float* __restrict__ ln_g,
    const float* __restrict__ ln_b, const float* __restrict__ w_offp,
    float* __restrict__ warp)
{
    const int p = blockIdx.x;
    const int c = threadIdx.x;
    const int lane = c & 63;
    const int wv = c >> 6;

    __shared__ float red[8];
    float v = t[(size_t)p * NC_ + c];

    float s = v;
#pragma unroll
    for (int o = 32; o > 0; o >>= 1) s += __shfl_down(s, o, 64);
    if (lane == 0) red[wv] = s;
    __syncthreads();
    float mu = (red[0] + red[1] + red[2] + red[3] + red[4] + red[5]) * (1.f / 384.f);
    __syncthreads();

    float d = v - mu;
    s = d * d;
#pragma unroll
    for (int o = 32; o > 0; o >>= 1) s += __shfl_down(s, o, 64);
    if (lane == 0) red[wv] = s;
    __syncthreads();
    float var = (red[0] + red[1] + red[2] + red[3] + red[4] + red[5]) * (1.f / 384.f);

    float nv = (v - mu) * rsqrtf(var + 1e-3f) * ln_g[c] + ln_b[c];
    float gv = 0.5f * nv * (1.0f + erff(nv * 0.70710678118654752440f));

    float s0 = gv * w_offp[lane * 2 + 0];
    float s1 = gv * w_offp[lane * 2 + 1];
#pragma unroll
    for (int o = 32; o > 0; o >>= 1) {
        s0 += __shfl_down(s0, o, 64);
        s1 += __shfl_down(s1, o, 64);
    }
    if (lane == 0) {
        int b = p >> 10, ij = p & 1023;
        int i = ij >> 5, j = ij & 31;
        float off0 = tanhf(s0) * 16.0f;
        float off1 = tanhf(s1) * 16.0f;
        float px = off1 + (float)i;
        float py = off0 + (float)j;
        int bg = b * NG + wv;
        warp[((size_t)bg * NQ + ij) * 2 + 0] = px;
        warp[((size_t)bg * NQ + ij) * 2 + 1] = py;
    }
}

// =====================================================================
// Bilinear sampling with zero border -> writes hi/lo bf16 directly.
// =====================================================================
__device__ inline float4 tap_load(const float* __restrict__ x, int b, int g,
                                  int yp, int xp, int ic4)
{
    int r = yp - 1, c = xp - 1;
    if ((unsigned)r < 32u && (unsigned)c < 32u)
        return *(const float4*)&x[(size_t)(((b * 32 + r) * 32 + c)) * NC_ + g * GC_ + ic4];
    return make_float4(0.f, 0.f, 0.f, 0.f);
}

__global__ __launch_bounds__(256) void sample_kk(
    const float* __restrict__ x, const float* __restrict__ warp,
    ushort* __restrict__ xs_hl)
{
    const int gidx = blockIdx.x * 256 + threadIdx.x;
    const int ic4 = (gidx & 15) * 4;
    const int qq = (gidx >> 4) & 1023;
    const int bg = gidx >> 14;
    const int b = bg / NG, g = bg % NG;

    const float wx = warp[((size_t)bg * NQ + qq) * 2 + 0];
    const float wy = warp[((size_t)bg * NQ + qq) * 2 + 1];
    const float xq = wx + 1.0f, yq = wy + 1.0f;
    float x0 = fminf(fmaxf(floorf(xq), 0.f), 32.f);
    float y0 = fminf(fmaxf(floorf(yq), 0.f), 32.f);
    float ax = fminf(fmaxf(xq - x0, 0.f), 1.f);
    float ay = fminf(fmaxf(yq - y0, 0.f), 1.f);
    int xi = (int)x0, yi = (int)y0;

    float4 tl = tap_load(x, b, g, yi,     xi,     ic4);
    float4 tr = tap_load(x, b, g, yi,     xi + 1, ic4);
    float4 bl = tap_load(x, b, g, yi + 1, xi,     ic4);
    float4 br = tap_load(x, b, g, yi + 1, xi + 1, ic4);

    float4 top, bot, r;
    top.x = tl.x + ax * (tr.x - tl.x); top.y = tl.y + ax * (tr.y - tl.y);
    top.z = tl.z + ax * (tr.z - tl.z); top.w = tl.w + ax * (tr.w - tl.w);
    bot.x = bl.x + ax * (br.x - bl.x); bot.y = bl.y + ax * (br.y - bl.y);
    bot.z = bl.z + ax * (br.z - bl.z); bot.w = bl.w + ax * (br.w - bl.w);
    r.x = top.x + ay * (bot.x - top.x); r.y = top.y + ay * (bot.y - top.y);
    r.z = top.z + ay * (bot.z - top.z); r.w = top.w + ay * (bot.w - top.w);

    ushort4 hi, lo;
    hi.x = f2bf(r.x); lo.x = f2bf(r.x - bf2f(hi.x));
    hi.y = f2bf(r.y); lo.y = f2bf(r.y - bf2f(hi.y));
    hi.z = f2bf(r.z); lo.z = f2bf(r.z - bf2f(hi.z));
    hi.w = f2bf(r.w); lo.w = f2bf(r.w - bf2f(hi.w));
    const size_t oidx = ((size_t)b * NQ + qq) * NC_ + g * GC_ + ic4;
    *(ushort4*)&xs_hl[oidx] = hi;
    *(ushort4*)&xs_hl[NPOS_ELEMS + oidx] = lo;
}

// =====================================================================
// V transpose: vb[b][n][384] bf16 (head slice) -> vt[b][h][c][n] bf16.
// =====================================================================
__global__ __launch_bounds__(256) void vtrans_k(
    const ushort* __restrict__ vb, ushort* __restrict__ vt)
{
    const int bid = blockIdx.x;
    const int nt = bid & 15;
    const int h = (bid >> 4) % NH;
    const int b = bid / (16 * NH);
    const int n0 = nt * 64;
    __shared__ __align__(16) ushort Ls[32][72];
    const int tid = threadIdx.x;
    {
        const int n = tid >> 2, c0 = (tid & 3) * 8;
        bf16x8 v = *(const bf16x8*)&vb[(size_t)(b * NQ + n0 + n) * NC_ + h * HC_ + c0];
#pragma unroll
        for (int j = 0; j < 8; ++j) Ls[c0 + j][n] = (ushort)v[j];
    }
    __syncthreads();
    {
        const int c = tid >> 3, n1 = (tid & 7) * 8;
        bf16x8 o = *(const bf16x8*)&Ls[c][n1];
        *(bf16x8*)&vt[(size_t)((b * NH + h) * HC_ + c) * NQ + n0 + n1] = o;
    }
}

// =====================================================================
// MFMA flash attention, dual independent key streams (0-511 / 512-1023)
// per wave, each with its own (m,l,O) online-softmax state, merged at end.
// Halves the serial chain depth, doubles ILP. Swapped-operand softmax
// (lane owns one query). K prefetched 1 tile ahead per stream.
// =====================================================================
__global__ __launch_bounds__(256) void attn_mfma3_k(
    const float* __restrict__ q, const ushort* __restrict__ kb,
    const ushort* __restrict__ vt, ushort* __restrict__ ohl)
{
    __shared__ __align__(16) ushort Pl[4][2][1024];   // per-wave, per-stream

    const int mt = blockIdx.x;
    const int bh = blockIdx.y;
    const int b = bh / NH, h = bh % NH;
    const int tid = threadIdx.x;
    const int w = tid >> 6;
    const int lane = tid & 63;
    const int c15 = lane & 15;
    const int lg = lane >> 4;

    const float scale = 0.17677669529663687f;

    bf16x8 qf;
    {
        const float* qp = &q[((size_t)b * NQ + mt * 64 + w * 16 + c15) * NC_ + h * HC_ + lg * 8];
        float tmp[8];
        *(float4*)&tmp[0] = *(const float4*)qp;
        *(float4*)&tmp[4] = *(const float4*)(qp + 4);
#pragma unroll
        for (int i = 0; i < 8; ++i) tmp[i] *= scale;
        qf = pack8(tmp);
    }

    f32x4 oA[2], oB[2];
    oA[0] = (f32x4){0.f,0.f,0.f,0.f}; oA[1] = (f32x4){0.f,0.f,0.f,0.f};
    oB[0] = (f32x4){0.f,0.f,0.f,0.f}; oB[1] = (f32x4){0.f,0.f,0.f,0.f};
    float mA = -INFINITY, lA = 0.f, mB = -INFINITY, lB = 0.f;

    const ushort* kbase = &kb[((size_t)b * NQ + c15) * NC_ + h * HC_ + lg * 8];
    const size_t vbase = (size_t)((b * NH + h) * HC_) * NQ + lg * 8;
    const int sw = (c15 & 7) << 3;
    const f32x4 z = (f32x4){0.f, 0.f, 0.f, 0.f};

    // prefetch K tile 0 of each stream
    bf16x8 kA[4], kB[4], knA[4], knB[4];
#pragma unroll
    for (int kt = 0; kt < 4; ++kt) {
        kA[kt] = *(const bf16x8*)(kbase + (size_t)(kt * 16) * NC_);
        kB[kt] = *(const bf16x8*)(kbase + (size_t)(512 + kt * 16) * NC_);
    }

    for (int t = 0; t < 8; ++t) {
        const int nA = t * 64;
        const int nB = 512 + t * 64;

        // V frags for both streams (needed only after softmax -> latency slack)
        bf16x8 vfA[4], vfB[4];
#pragma unroll
        for (int kblk = 0; kblk < 2; ++kblk)
#pragma unroll
            for (int ct = 0; ct < 2; ++ct) {
                vfA[kblk * 2 + ct] = *(const bf16x8*)&vt[vbase + (size_t)(ct * 16 + c15) * NQ + nA + kblk * 32];
                vfB[kblk * 2 + ct] = *(const bf16x8*)&vt[vbase + (size_t)(ct * 16 + c15) * NQ + nB + kblk * 32];
            }
        // prefetch next K tiles
        if (t < 7) {
#pragma unroll
            for (int kt = 0; kt < 4; ++kt) {
                knA[kt] = *(const bf16x8*)(kbase + (size_t)(nA + 64 + kt * 16) * NC_);
                knB[kt] = *(const bf16x8*)(kbase + (size_t)(nB + 64 + kt * 16) * NC_);
            }
        }

        // S = K.Q^T for both streams (independent MFMA batches)
        f32x4 sA[4], sB[4];
#pragma unroll
        for (int kt = 0; kt < 4; ++kt) {
            sA[kt] = __builtin_amdgcn_mfma_f32_16x16x32_bf16(kA[kt], qf, z, 0, 0, 0);
            sB[kt] = __builtin_amdgcn_mfma_f32_16x16x32_bf16(kB[kt], qf, z, 0, 0, 0);
        }

        // two independent in-lane softmax chains
        float mxA = -INFINITY, mxB = -INFINITY;
#pragma unroll
        for (int kt = 0; kt < 4; ++kt)
#pragma unroll
            for (int r = 0; r < 4; ++r) {
                mxA = fmaxf(mxA, sA[kt][r]);
                mxB = fmaxf(mxB, sB[kt][r]);
            }
        mxA = fmaxf(mxA, __shfl_xor(mxA, 16, 64));
        mxB = fmaxf(mxB, __shfl_xor(mxB, 16, 64));
        mxA = fmaxf(mxA, __shfl_xor(mxA, 32, 64));
        mxB = fmaxf(mxB, __shfl_xor(mxB, 32, 64));
        float mnA = fmaxf(mA, mxA), mnB = fmaxf(mB, mxB);
        float alA = __expf(mA - mnA), alB = __expf(mB - mnB);
        mA = mnA; mB = mnB;

        float rsA = 0.f, rsB = 0.f;
#pragma unroll
        for (int kt = 0; kt < 4; ++kt) {
            ushort4 pkA, pkB;
            float pa0 = __expf(sA[kt][0] - mnA), pb0 = __expf(sB[kt][0] - mnB);
            float pa1 = __expf(sA[kt][1] - mnA), pb1 = __expf(sB[kt][1] - mnB);
            float pa2 = __expf(sA[kt][2] - mnA), pb2 = __expf(sB[kt][2] - mnB);
            float pa3 = __expf(sA[kt][3] - mnA), pb3 = __expf(sB[kt][3] - mnB);
            rsA += pa0 + pa1 + pa2 + pa3;
            rsB += pb0 + pb1 + pb2 + pb3;
            pkA.x = f2bf(pa0); pkA.y = f2bf(pa1); pkA.z = f2bf(pa2); pkA.w = f2bf(pa3);
            pkB.x = f2bf(pb0); pkB.y = f2bf(pb1); pkB.z = f2bf(pb2); pkB.w = f2bf(pb3);
            const int pidx = c15 * 64 + ((kt * 16 + lg * 4) ^ sw);
            *(ushort4*)&Pl[w][0][pidx] = pkA;
            *(ushort4*)&Pl[w][1][pidx] = pkB;
        }
        rsA += __shfl_xor(rsA, 16, 64);
        rsB += __shfl_xor(rsB, 16, 64);
        rsA += __shfl_xor(rsA, 32, 64);
        rsB += __shfl_xor(rsB, 32, 64);
        lA = lA * alA + rsA;
        lB = lB * alB + rsB;

        // alpha broadcast to O layout (query = lg*4+r) + rescale
#pragma unroll
        for (int r = 0; r < 4; ++r) {
            float aa = __shfl(alA, lg * 4 + r, 64);
            float ab = __shfl(alB, lg * 4 + r, 64);
            oA[0][r] *= aa; oA[1][r] *= aa;
            oB[0][r] *= ab; oB[1][r] *= ab;
        }

        // O += P.V for both streams
#pragma unroll
        for (int kblk = 0; kblk < 2; ++kblk) {
            const int pidx = c15 * 64 + ((kblk * 32 + lg * 8) ^ sw);
            bf16x8 pfA = *(bf16x8*)&Pl[w][0][pidx];
            bf16x8 pfB = *(bf16x8*)&Pl[w][1][pidx];
            oA[0] = __builtin_amdgcn_mfma_f32_16x16x32_bf16(pfA, vfA[kblk * 2 + 0], oA[0], 0, 0, 0);
            oA[1] = __builtin_amdgcn_mfma_f32_16x16x32_bf16(pfA, vfA[kblk * 2 + 1], oA[1], 0, 0, 0);
            oB[0] = __builtin_amdgcn_mfma_f32_16x16x32_bf16(pfB, vfB[kblk * 2 + 0], oB[0], 0, 0, 0);
            oB[1] = __builtin_amdgcn_mfma_f32_16x16x32_bf16(pfB, vfB[kblk * 2 + 1], oB[1], 0, 0, 0);
        }

        if (t < 7) {
#pragma unroll
            for (int kt = 0; kt < 4; ++kt) { kA[kt] = knA[kt]; kB[kt] = knB[kt]; }
        }
    }

    // merge streams: m* = max(mA,mB); O = OA e^{mA-m*} + OB e^{mB-m*}; l likewise
    float mM = fmaxf(mA, mB);
    float aA = __expf(mA - mM);
    float aB = __expf(mB - mM);
    float linv = 1.f / (lA * aA + lB * aB);

#pragma unroll
    for (int r = 0; r < 4; ++r) {
        const float aAr = __shfl(aA, lg * 4 + r, 64);
        const float aBr = __shfl(aB, lg * 4 + r, 64);
        const float lir = __shfl(linv, lg * 4 + r, 64);
        const size_t row = (size_t)b * NQ + mt * 64 + w * 16 + lg * 4 + r;
#pragma unroll
        for (int ct = 0; ct < 2; ++ct) {
            const float val = (oA[ct][r] * aAr + oB[ct][r] * aBr) * lir;
            const ushort hh = f2bf(val);
            const size_t idx = row * NC_ + h * HC_ + ct * 16 + c15;
            ohl[idx] = hh;
            ohl[NPOS_ELEMS + idx] = f2bf(val - bf2f(hh));
        }
    }
}

// =====================================================================
// Launch. ws floats (NPOS = 3,145,728):
// slot0: q fp32 | slot1: t fp32 | slot2: xs hi/lo, later attn-out hi/lo
// slot3: x hi/lo (early), later kb16|vb16 | slot4: vt | wtc | wtsq
// slot5 (at 5*NPOS): warp coords
// =====================================================================
extern "C" void kernel_launch(void* const* d_in, const int* in_sizes, int n_in,
                              void* d_out, int out_size, void* d_ws, size_t ws_size,
                              hipStream_t stream)
{
    const float* x      = (const float*)d_in[0];
    const float* w_q    = (const float*)d_in[1];
    const float* b_q    = (const float*)d_in[2];
    const float* w_off0 = (const float*)d_in[3];
    const float* b_off0 = (const float*)d_in[4];
    const float* ln_g   = (const float*)d_in[5];
    const float* ln_b   = (const float*)d_in[6];
    const float* w_offp = (const float*)d_in[7];
    const float* w_k    = (const float*)d_in[8];
    const float* b_k    = (const float*)d_in[9];
    const float* w_v    = (const float*)d_in[10];
    const float* b_v    = (const float*)d_in[11];
    const float* w_o    = (const float*)d_in[12];
    const float* b_o    = (const float*)d_in[13];

    float* ws = (float*)d_ws;
    float*  q     = ws;
    float*  t     = ws + (size_t)NPOS_ELEMS;
    ushort* xs_hl = (ushort*)(ws + (size_t)2 * NPOS_ELEMS);  // also attn-out hi/lo
    ushort* xhl   = (ushort*)(ws + (size_t)3 * NPOS_ELEMS);  // dead before kb16
    ushort* kb16  = (ushort*)(ws + (size_t)3 * NPOS_ELEMS);
    ushort* vb16  = kb16 + NPOS_ELEMS;
    ushort* vt    = (ushort*)(ws + (size_t)4 * NPOS_ELEMS);
    ushort* wtc   = vt + NPOS_ELEMS;
    ushort* wtsq  = wtc + 2 * WT_ELEMS;
    float*  wp    = ws + (size_t)5 * NPOS_ELEMS;

    ushort* wtq = wtsq;
    ushort* wtk = wtsq + 2 * WSQ;
    ushort* wtv = wtsq + 4 * WSQ;
    ushort* wto = wtsq + 6 * WSQ;

    const int M = BB * NQ;   // 8192

    wconv_t_k<<<WT_ELEMS / 256, 256, 0, stream>>>(w_off0, wtc);
    wsplit_k<<<dim3(6, 6, 4), 256, 0, stream>>>(w_q, w_k, w_v, w_o, wtsq);
    split_k<<<NPOS_ELEMS / 1024, 256, 0, stream>>>(x, xhl, NPOS_ELEMS);
    gemm_gl_k<0><<<dim3(M / 64, 6), 256, 0, stream>>>(xhl, wtq, b_q, (void*)q, M);
    conv_mfma_k<<<BB * 8 * NG, 256, 0, stream>>>(q, wtc, b_off0, t);
    ln_gelu_off_k<<<M, 384, 0, stream>>>(t, ln_g, ln_b, w_offp, wp);
    sample_kk<<<(BB * NG * NQ * 16) / 256, 256, 0, stream>>>(x, wp, xs_hl);
    gemm_gl_k<1><<<dim3(M / 64, 6), 256, 0, stream>>>(xs_hl, wtk, b_k, (void*)kb16, M);
    gemm_gl_k<1><<<dim3(M / 64, 6), 256, 0, stream>>>(xs_hl, wtv, b_v, (void*)vb16, M);
    vtrans_k<<<BB * NH * 16, 256, 0, stream>>>(vb16, vt);
    attn_mfma3_k<<<dim3(NQ / 64, BB * NH), 256, 0, stream>>>(q, kb16, vt, xs_hl);
    gemm_gl_k<0><<<dim3(M / 64, 6), 256, 0, stream>>>(xs_hl, wto, b_o, d_out, M);
}

// Round 7
// 253.528 us; speedup vs baseline: 1.6137x; 1.6137x over previous
//
#include <hip/hip_runtime.h>
#include <hip/hip_bf16.h>
#include <math.h>

// Problem sizes (fixed)
#define BB 8
#define NC_ 384
#define NG 6
#define GC_ 64
#define NH 12
#define HC_ 32
#define NQ 1024
#define NPOS_ELEMS (BB*NQ*NC_)       // 3,145,728
#define WT_ELEMS (NG*9*GC_*GC_)      // 221,184 per conv split plane
#define WSQ (NC_*NC_)                // 147,456 per square-weight plane

typedef short bf16x8 __attribute__((ext_vector_type(8)));
typedef float f32x4  __attribute__((ext_vector_type(4)));

__device__ inline ushort f2bf(float f) {
    union { float f; unsigned u; } v; v.f = f;
    unsigned r = v.u + 0x7FFFu + ((v.u >> 16) & 1u);   // RNE
    return (ushort)(r >> 16);
}
__device__ inline float bf2f(ushort h) {
    union { unsigned u; float f; } v; v.u = ((unsigned)h) << 16;
    return v.f;
}
__device__ inline bf16x8 pack8(const float* f) {
    bf16x8 r;
#pragma unroll
    for (int i = 0; i < 8; ++i) r[i] = (short)f2bf(f[i]);
    return r;
}
__device__ inline ushort2 pk2(float a, float b) {
    union { __hip_bfloat162 h; ushort2 u; } c;
    c.h = __float22bfloat162_rn(make_float2(a, b));
    return c.u;
}

// =====================================================================
// fp32 -> hi/lo bf16 split (hi at [0,n), lo at [n,2n)).
// =====================================================================
__global__ __launch_bounds__(256) void split_k(
    const float* __restrict__ in, ushort* __restrict__ out, int n)
{
    const int i = (blockIdx.x * 256 + threadIdx.x) * 4;
    float4 v = *(const float4*)&in[i];
    ushort4 hi, lo;
    hi.x = f2bf(v.x); lo.x = f2bf(v.x - bf2f(hi.x));
    hi.y = f2bf(v.y); lo.y = f2bf(v.y - bf2f(hi.y));
    hi.z = f2bf(v.z); lo.z = f2bf(v.z - bf2f(hi.z));
    hi.w = f2bf(v.w); lo.w = f2bf(v.w - bf2f(hi.w));
    *(ushort4*)&out[i] = hi;
    *(ushort4*)&out[n + i] = lo;
}

// =====================================================================
// Square weight -> FRAGMENT-MAJOR split pack.
// wt[mat][plane][nt(24)][kk(12)][lane(64)][8]:
//   elem j of (nt,kk,lane) = W[kk*32+(lane>>4)*8+j][nt*16+(lane&15)].
// One wave-load of a fragment group = 1KB contiguous.
// =====================================================================
__global__ __launch_bounds__(256) void wsplit_k(
    const float* __restrict__ w0, const float* __restrict__ w1,
    const float* __restrict__ w2, const float* __restrict__ w3,
    ushort* __restrict__ wt)
{
    const int mat = blockIdx.z;
    const float* W = mat == 0 ? w0 : mat == 1 ? w1 : mat == 2 ? w2 : w3;
    const int kt0 = blockIdx.x * 64, nt0 = blockIdx.y * 64;
    __shared__ float Ts[64][68];
    const int tid = threadIdx.x;
    {
        const int kl = tid >> 4, nl = (tid & 15) * 4;
#pragma unroll
        for (int rr = 0; rr < 4; ++rr)
            *(float4*)&Ts[kl + rr * 16][nl] =
                *(const float4*)&W[(size_t)(kt0 + kl + rr * 16) * NC_ + nt0 + nl];
    }
    __syncthreads();
    const size_t mbase = (size_t)mat * 2 * WSQ;
#pragma unroll
    for (int s = 0; s < 2; ++s) {
        const int slot = s * 256 + tid;       // 0..511
        const int l = slot & 63;
        const int kk_l = (slot >> 6) & 1;
        const int nt_l = slot >> 7;           // 0..3
        bf16x8 hi8, lo8;
#pragma unroll
        for (int j = 0; j < 8; ++j) {
            float f = Ts[kk_l * 32 + (l >> 4) * 8 + j][nt_l * 16 + (l & 15)];
            ushort h = f2bf(f);
            hi8[j] = (short)h;
            lo8[j] = (short)f2bf(f - bf2f(h));
        }
        const size_t fidx = (((size_t)((nt0 >> 4) + nt_l)) * 12 + ((kt0 >> 5) + kk_l)) * 64 + l;
        *(bf16x8*)&wt[mbase + fidx * 8] = hi8;
        *(bf16x8*)&wt[mbase + WSQ + fidx * 8] = lo8;
    }
}

// =====================================================================
// Split-bf16 MFMA GEMM, fp32 out, packed-fragment B. A pre-split hi/lo,
// staged via swizzled LDS (validated R5 structure).
// =====================================================================
__global__ __launch_bounds__(256) void gemm_sq_k(
    const ushort* __restrict__ Ahl, const ushort* __restrict__ Wt,
    const float* __restrict__ bias, float* __restrict__ C, int M)
{
    __shared__ __align__(16) ushort At[2][64 * 64];
    const size_t alo = (size_t)M * NC_;
    const int m0 = blockIdx.x * 64;
    const int n0 = blockIdx.y * 64;
    const int ntb = n0 >> 4;
    const int tid = threadIdx.x;
    const int w = tid >> 6;
    const int lane = tid & 63;
    const int c15 = lane & 15;
    const int lg = lane >> 4;

    f32x4 acc[4];
#pragma unroll
    for (int ct = 0; ct < 4; ++ct) acc[ct] = (f32x4){0.f, 0.f, 0.f, 0.f};

    const int sr = tid >> 2;
    const int sc = (tid & 3) * 16;

    for (int ks = 0; ks < NC_; ks += 64) {
        const ushort* a0 = &Ahl[(size_t)(m0 + sr) * NC_ + ks + sc];
        bf16x8 h0 = *(const bf16x8*)a0;
        bf16x8 h1 = *(const bf16x8*)(a0 + 8);
        bf16x8 l0 = *(const bf16x8*)(a0 + alo);
        bf16x8 l1 = *(const bf16x8*)(a0 + alo + 8);
        const int i0 = sr * 64 + (sc ^ ((sr & 7) << 3));
        const int i1 = sr * 64 + ((sc + 8) ^ ((sr & 7) << 3));
        __syncthreads();
        *(bf16x8*)&At[0][i0] = h0;
        *(bf16x8*)&At[0][i1] = h1;
        *(bf16x8*)&At[1][i0] = l0;
        *(bf16x8*)&At[1][i1] = l1;
        __syncthreads();
#pragma unroll
        for (int kc = 0; kc < 64; kc += 32) {
            const int arow = w * 16 + c15;
            const int aidx = arow * 64 + ((kc + lg * 8) ^ ((arow & 7) << 3));
            bf16x8 Ah = *(bf16x8*)&At[0][aidx];
            bf16x8 Al = *(bf16x8*)&At[1][aidx];
            const int kk = (ks + kc) >> 5;
#pragma unroll
            for (int ct = 0; ct < 4; ++ct) {
                const size_t fo = ((size_t)(ntb + ct) * 12 + kk) * 512 + lane * 8;
                bf16x8 Bh = *(const bf16x8*)&Wt[fo];
                bf16x8 Bl = *(const bf16x8*)&Wt[WSQ + fo];
                acc[ct] = __builtin_amdgcn_mfma_f32_16x16x32_bf16(Ah, Bh, acc[ct], 0, 0, 0);
                acc[ct] = __builtin_amdgcn_mfma_f32_16x16x32_bf16(Al, Bh, acc[ct], 0, 0, 0);
                acc[ct] = __builtin_amdgcn_mfma_f32_16x16x32_bf16(Ah, Bl, acc[ct], 0, 0, 0);
            }
        }
    }

#pragma unroll
    for (int ct = 0; ct < 4; ++ct) {
        const int col = n0 + ct * 16 + c15;
        const float bv = bias[col];
#pragma unroll
        for (int r = 0; r < 4; ++r) {
            const size_t row = m0 + w * 16 + lg * 4 + r;
            C[row * NC_ + col] = acc[ct][r] + bv;
        }
    }
}

// =====================================================================
// FUSED K+V GEMM (shared A tile, both outputs bf16), packed-fragment B.
// =====================================================================
__global__ __launch_bounds__(256) void gemm_kv_k(
    const ushort* __restrict__ Ahl, const ushort* __restrict__ WtK,
    const ushort* __restrict__ WtV, const float* __restrict__ bK,
    const float* __restrict__ bV, ushort* __restrict__ CK,
    ushort* __restrict__ CV, int M)
{
    __shared__ __align__(16) ushort At[2][64 * 64];
    const size_t alo = (size_t)M * NC_;
    const int m0 = blockIdx.x * 64;
    const int n0 = blockIdx.y * 64;
    const int ntb = n0 >> 4;
    const int tid = threadIdx.x;
    const int w = tid >> 6;
    const int lane = tid & 63;
    const int c15 = lane & 15;
    const int lg = lane >> 4;

    f32x4 aK[4], aV[4];
#pragma unroll
    for (int ct = 0; ct < 4; ++ct) {
        aK[ct] = (f32x4){0.f, 0.f, 0.f, 0.f};
        aV[ct] = (f32x4){0.f, 0.f, 0.f, 0.f};
    }

    const int sr = tid >> 2;
    const int sc = (tid & 3) * 16;

    for (int ks = 0; ks < NC_; ks += 64) {
        const ushort* a0 = &Ahl[(size_t)(m0 + sr) * NC_ + ks + sc];
        bf16x8 h0 = *(const bf16x8*)a0;
        bf16x8 h1 = *(const bf16x8*)(a0 + 8);
        bf16x8 l0 = *(const bf16x8*)(a0 + alo);
        bf16x8 l1 = *(const bf16x8*)(a0 + alo + 8);
        const int i0 = sr * 64 + (sc ^ ((sr & 7) << 3));
        const int i1 = sr * 64 + ((sc + 8) ^ ((sr & 7) << 3));
        __syncthreads();
        *(bf16x8*)&At[0][i0] = h0;
        *(bf16x8*)&At[0][i1] = h1;
        *(bf16x8*)&At[1][i0] = l0;
        *(bf16x8*)&At[1][i1] = l1;
        __syncthreads();
#pragma unroll
        for (int kc = 0; kc < 64; kc += 32) {
            const int arow = w * 16 + c15;
            const int aidx = arow * 64 + ((kc + lg * 8) ^ ((arow & 7) << 3));
            bf16x8 Ah = *(bf16x8*)&At[0][aidx];
            bf16x8 Al = *(bf16x8*)&At[1][aidx];
            const int kk = (ks + kc) >> 5;
#pragma unroll
            for (int ct = 0; ct < 4; ++ct) {
                const size_t fo = ((size_t)(ntb + ct) * 12 + kk) * 512 + lane * 8;
                bf16x8 BKh = *(const bf16x8*)&WtK[fo];
                bf16x8 BKl = *(const bf16x8*)&WtK[WSQ + fo];
                aK[ct] = __builtin_amdgcn_mfma_f32_16x16x32_bf16(Ah, BKh, aK[ct], 0, 0, 0);
                aK[ct] = __builtin_amdgcn_mfma_f32_16x16x32_bf16(Al, BKh, aK[ct], 0, 0, 0);
                aK[ct] = __builtin_amdgcn_mfma_f32_16x16x32_bf16(Ah, BKl, aK[ct], 0, 0, 0);
                bf16x8 BVh = *(const bf16x8*)&WtV[fo];
                bf16x8 BVl = *(const bf16x8*)&WtV[WSQ + fo];
                aV[ct] = __builtin_amdgcn_mfma_f32_16x16x32_bf16(Ah, BVh, aV[ct], 0, 0, 0);
                aV[ct] = __builtin_amdgcn_mfma_f32_16x16x32_bf16(Al, BVh, aV[ct], 0, 0, 0);
                aV[ct] = __builtin_amdgcn_mfma_f32_16x16x32_bf16(Ah, BVl, aV[ct], 0, 0, 0);
            }
        }
    }

#pragma unroll
    for (int ct = 0; ct < 4; ++ct) {
        const int col = n0 + ct * 16 + c15;
        const float bvK = bK[col];
        const float bvV = bV[col];
#pragma unroll
        for (int r = 0; r < 4; ++r) {
            const size_t row = m0 + w * 16 + lg * 4 + r;
            CK[row * NC_ + col] = f2bf(aK[ct][r] + bvK);
            CV[row * NC_ + col] = f2bf(aV[ct][r] + bvV);
        }
    }
}

// =====================================================================
// Conv weight -> FRAGMENT-MAJOR split pack:
// wt[plane][g][tap][ot(4)][kc2(2)][lane(64)][8]:
//   elem j = w[tap][ic=kc2*32+(lane>>4)*8+j][g*64 + ot*16+(lane&15)].
// =====================================================================
__global__ __launch_bounds__(256) void wconv_t_k(
    const float* __restrict__ w, ushort* __restrict__ wt)
{
    const int i = blockIdx.x * 256 + threadIdx.x;   // < 27648
    const int l = i & 63;
    const int kc2 = (i >> 6) & 1;
    const int ot = (i >> 7) & 3;
    const int tapg = i >> 9;          // g*9+tap
    const int tap = tapg % 9, g = tapg / 9;
    bf16x8 hi8, lo8;
#pragma unroll
    for (int j = 0; j < 8; ++j) {
        const int ic = kc2 * 32 + (l >> 4) * 8 + j;
        const int oc = ot * 16 + (l & 15);
        float v = w[(size_t)(tap * GC_ + ic) * NC_ + g * GC_ + oc];
        ushort h = f2bf(v);
        hi8[j] = (short)h;
        lo8[j] = (short)f2bf(v - bf2f(h));
    }
    *(bf16x8*)&wt[(size_t)i * 8] = hi8;
    *(bf16x8*)&wt[WT_ELEMS + (size_t)i * 8] = lo8;
}

// =====================================================================
// Grouped 3x3 conv, split-bf16 MFMA, packed-fragment weights.
// =====================================================================
__global__ __launch_bounds__(256) void conv_mfma_k(
    const float* __restrict__ q, const ushort* __restrict__ wt,
    const float* __restrict__ bias, float* __restrict__ t)
{
    const int bid = blockIdx.x;
    const int g = bid % NG;
    const int rg = (bid / NG) & 7;
    const int b = bid / (NG * 8);
    const int y0 = rg * 4;

    __shared__ __align__(16) ushort At[2][6 * 34 * 64];

    const int tid = threadIdx.x;
    const int wv = tid >> 6;
    const int lane = tid & 63;
    const int c15 = lane & 15;
    const int lg = lane >> 4;
    const int oc = wv * 16 + c15;

    for (int idx = tid; idx < 6 * 34 * 8; idx += 256) {
        const int cell = idx >> 3;
        const int ch0 = (idx & 7) << 3;
        const int rr = cell / 34, cc = cell % 34;
        const int yy = y0 + rr - 1, xx = cc - 1;
        float v[8];
        if ((unsigned)yy < 32u && (unsigned)xx < 32u) {
            const float* src = &q[(size_t)((b * 32 + yy) * 32 + xx) * NC_ + g * GC_ + ch0];
            *(float4*)&v[0] = *(const float4*)src;
            *(float4*)&v[4] = *(const float4*)(src + 4);
        } else {
#pragma unroll
            for (int j = 0; j < 8; ++j) v[j] = 0.f;
        }
        bf16x8 hi8, lo8;
#pragma unroll
        for (int j = 0; j < 8; ++j) {
            ushort h = f2bf(v[j]);
            hi8[j] = (short)h;
            lo8[j] = (short)f2bf(v[j] - bf2f(h));
        }
        const int wi = cell * 64 + (ch0 ^ ((cc & 7) << 3));
        *(bf16x8*)&At[0][wi] = hi8;
        *(bf16x8*)&At[1][wi] = lo8;
    }

    const float bval = bias[g * GC_ + oc];
    f32x4 acc[8];
#pragma unroll
    for (int m = 0; m < 8; ++m) acc[m] = (f32x4){bval, bval, bval, bval};

    __syncthreads();

#pragma unroll
    for (int tap = 0; tap < 9; ++tap) {
        const int kh = tap / 3, kw = tap % 3;
        const size_t f0 = ((size_t)(((g * 9 + tap) * 4 + wv) * 2)) * 512 + lane * 8;
        bf16x8 Bh0 = *(const bf16x8*)&wt[f0];
        bf16x8 Bh1 = *(const bf16x8*)&wt[f0 + 512];
        bf16x8 Bl0 = *(const bf16x8*)&wt[WT_ELEMS + f0];
        bf16x8 Bl1 = *(const bf16x8*)&wt[WT_ELEMS + f0 + 512];
#pragma unroll
        for (int m = 0; m < 8; ++m) {
            const int rr = (m >> 1) + kh;
            const int cc = (m & 1) * 16 + kw + c15;
            const int base = (rr * 34 + cc) * 64;
            const int sw = (cc & 7) << 3;
            bf16x8 Ah0 = *(const bf16x8*)&At[0][base + ((lg * 8) ^ sw)];
            bf16x8 Ah1 = *(const bf16x8*)&At[0][base + ((32 + lg * 8) ^ sw)];
            bf16x8 Al0 = *(const bf16x8*)&At[1][base + ((lg * 8) ^ sw)];
            bf16x8 Al1 = *(const bf16x8*)&At[1][base + ((32 + lg * 8) ^ sw)];
            acc[m] = __builtin_amdgcn_mfma_f32_16x16x32_bf16(Ah0, Bh0, acc[m], 0, 0, 0);
            acc[m] = __builtin_amdgcn_mfma_f32_16x16x32_bf16(Ah1, Bh1, acc[m], 0, 0, 0);
            acc[m] = __builtin_amdgcn_mfma_f32_16x16x32_bf16(Al0, Bh0, acc[m], 0, 0, 0);
            acc[m] = __builtin_amdgcn_mfma_f32_16x16x32_bf16(Al1, Bh1, acc[m], 0, 0, 0);
            acc[m] = __builtin_amdgcn_mfma_f32_16x16x32_bf16(Ah0, Bl0, acc[m], 0, 0, 0);
            acc[m] = __builtin_amdgcn_mfma_f32_16x16x32_bf16(Ah1, Bl1, acc[m], 0, 0, 0);
        }
    }

#pragma unroll
    for (int m = 0; m < 8; ++m) {
        const int y = y0 + (m >> 1);
#pragma unroll
        for (int r = 0; r < 4; ++r) {
            const int x = (m & 1) * 16 + lg * 4 + r;
            t[(size_t)((b * 32 + y) * 32 + x) * NC_ + g * GC_ + oc] = acc[m][r];
        }
    }
}

// =====================================================================
// LayerNorm(384) + erf-GELU + per-group 64->2 proj + tanh*16 + ref grid.
// =====================================================================
__global__ __launch_bounds__(384) void ln_gelu_off_k(
    const float* __restrict__ t, const float* __restrict__ ln_g,
    const float* __restrict__ ln_b, const float* __restrict__ w_offp,
    float* __restrict__ warp)
{
    const int p = blockIdx.x;
    const int c = threadIdx.x;
    const int lane = c & 63;
    const int wv = c >> 6;

    __shared__ float red[8];
    float v = t[(size_t)p * NC_ + c];

    float s = v;
#pragma unroll
    for (int o = 32; o > 0; o >>= 1) s += __shfl_down(s, o, 64);
    if (lane == 0) red[wv] = s;
    __syncthreads();
    float mu = (red[0] + red[1] + red[2] + red[3] + red[4] + red[5]) * (1.f / 384.f);
    __syncthreads();

    float d = v - mu;
    s = d * d;
#pragma unroll
    for (int o = 32; o > 0; o >>= 1) s += __shfl_down(s, o, 64);
    if (lane == 0) red[wv] = s;
    __syncthreads();
    float var = (red[0] + red[1] + red[2] + red[3] + red[4] + red[5]) * (1.f / 384.f);

    float nv = (v - mu) * rsqrtf(var + 1e-3f) * ln_g[c] + ln_b[c];
    float gv = 0.5f * nv * (1.0f + erff(nv * 0.70710678118654752440f));

    float s0 = gv * w_offp[lane * 2 + 0];
    float s1 = gv * w_offp[lane * 2 + 1];
#pragma unroll
    for (int o = 32; o > 0; o >>= 1) {
        s0 += __shfl_down(s0, o, 64);
        s1 += __shfl_down(s1, o, 64);
    }
    if (lane == 0) {
        int b = p >> 10, ij = p & 1023;
        int i = ij >> 5, j = ij & 31;
        float off0 = tanhf(s0) * 16.0f;
        float off1 = tanhf(s1) * 16.0f;
        float px = off1 + (float)i;
        float py = off0 + (float)j;
        int bg = b * NG + wv;
        warp[((size_t)bg * NQ + ij) * 2 + 0] = px;
        warp[((size_t)bg * NQ + ij) * 2 + 1] = py;
    }
}

// =====================================================================
// Bilinear sampling with zero border -> hi/lo bf16 (unchanged).
// =====================================================================
__device__ inline float4 tap_load(const float* __restrict__ x, int b, int g,
                                  int yp, int xp, int ic4)
{
    int r = yp - 1, c = xp - 1;
    if ((unsigned)r < 32u && (unsigned)c < 32u)
        return *(const float4*)&x[(size_t)(((b * 32 + r) * 32 + c)) * NC_ + g * GC_ + ic4];
    return make_float4(0.f, 0.f, 0.f, 0.f);
}

__global__ __launch_bounds__(256) void sample_kk(
    const float* __restrict__ x, const float* __restrict__ warp,
    ushort* __restrict__ xs_hl)
{
    const int gidx = blockIdx.x * 256 + threadIdx.x;
    const int ic4 = (gidx & 15) * 4;
    const int qq = (gidx >> 4) & 1023;
    const int bg = gidx >> 14;
    const int b = bg / NG, g = bg % NG;

    const float wx = warp[((size_t)bg * NQ + qq) * 2 + 0];
    const float wy = warp[((size_t)bg * NQ + qq) * 2 + 1];
    const float xq = wx + 1.0f, yq = wy + 1.0f;
    float x0 = fminf(fmaxf(floorf(xq), 0.f), 32.f);
    float y0 = fminf(fmaxf(floorf(yq), 0.f), 32.f);
    float ax = fminf(fmaxf(xq - x0, 0.f), 1.f);
    float ay = fminf(fmaxf(yq - y0, 0.f), 1.f);
    int xi = (int)x0, yi = (int)y0;

    float4 tl = tap_load(x, b, g, yi,     xi,     ic4);
    float4 tr = tap_load(x, b, g, yi,     xi + 1, ic4);
    float4 bl = tap_load(x, b, g, yi + 1, xi,     ic4);
    float4 br = tap_load(x, b, g, yi + 1, xi + 1, ic4);

    float4 top, bot, r;
    top.x = tl.x + ax * (tr.x - tl.x); top.y = tl.y + ax * (tr.y - tl.y);
    top.z = tl.z + ax * (tr.z - tl.z); top.w = tl.w + ax * (tr.w - tl.w);
    bot.x = bl.x + ax * (br.x - bl.x); bot.y = bl.y + ax * (br.y - bl.y);
    bot.z = bl.z + ax * (br.z - bl.z); bot.w = bl.w + ax * (br.w - bl.w);
    r.x = top.x + ay * (bot.x - top.x); r.y = top.y + ay * (bot.y - top.y);
    r.z = top.z + ay * (bot.z - top.z); r.w = top.w + ay * (bot.w - top.w);

    ushort4 hi, lo;
    hi.x = f2bf(r.x); lo.x = f2bf(r.x - bf2f(hi.x));
    hi.y = f2bf(r.y); lo.y = f2bf(r.y - bf2f(hi.y));
    hi.z = f2bf(r.z); lo.z = f2bf(r.z - bf2f(hi.z));
    hi.w = f2bf(r.w); lo.w = f2bf(r.w - bf2f(hi.w));
    const size_t oidx = ((size_t)b * NQ + qq) * NC_ + g * GC_ + ic4;
    *(ushort4*)&xs_hl[oidx] = hi;
    *(ushort4*)&xs_hl[NPOS_ELEMS + oidx] = lo;
}

// =====================================================================
// V transpose: vb[b][n][384] bf16 (head slice) -> vt[b][h][c][n] bf16.
// =====================================================================
__global__ __launch_bounds__(256) void vtrans_k(
    const ushort* __restrict__ vb, ushort* __restrict__ vt)
{
    const int bid = blockIdx.x;
    const int nt = bid & 15;
    const int h = (bid >> 4) % NH;
    const int b = bid / (16 * NH);
    const int n0 = nt * 64;
    __shared__ __align__(16) ushort Ls[32][72];
    const int tid = threadIdx.x;
    {
        const int n = tid >> 2, c0 = (tid & 3) * 8;
        bf16x8 v = *(const bf16x8*)&vb[(size_t)(b * NQ + n0 + n) * NC_ + h * HC_ + c0];
#pragma unroll
        for (int j = 0; j < 8; ++j) Ls[c0 + j][n] = (ushort)v[j];
    }
    __syncthreads();
    {
        const int c = tid >> 3, n1 = (tid & 7) * 8;
        bf16x8 o = *(const bf16x8*)&Ls[c][n1];
        *(bf16x8*)&vt[(size_t)((b * NH + h) * HC_ + c) * NQ + n0 + n1] = o;
    }
}

// =====================================================================
// K/V -> FRAGMENT-MAJOR pack for attention.
// kp[bh][t(16)][kt(4)][lane(64)][8]: elem j = K[t*64+kt*16+(l&15)][(l>>4)*8+j]
// vp[bh][t(16)][kblk(2)][ct(2)][lane(64)][8]:
//   elem j = V[t*64+kblk*32+(l>>4)*8+j][ct*16+(l&15)]  (from vt, contiguous)
// =====================================================================
__global__ __launch_bounds__(256) void kvpack_k(
    const ushort* __restrict__ kb, const ushort* __restrict__ vt,
    ushort* __restrict__ kp, ushort* __restrict__ vp)
{
    const int i = blockIdx.x * 256 + threadIdx.x;   // < 96*4096
    const int l = i & 63;
    {
        const int kt = (i >> 6) & 3;
        const int t = (i >> 8) & 15;
        const int bh = i >> 12;
        const int b = bh / NH, h = bh % NH;
        const int n = t * 64 + kt * 16 + (l & 15);
        bf16x8 v = *(const bf16x8*)&kb[((size_t)b * NQ + n) * NC_ + h * HC_ + (l >> 4) * 8];
        *(bf16x8*)&kp[(size_t)i * 8] = v;
    }
    {
        const int ct = (i >> 6) & 1;
        const int kblk = (i >> 7) & 1;
        const int t = (i >> 8) & 15;
        const int bh = i >> 12;
        const int c = ct * 16 + (l & 15);
        const int n = t * 64 + kblk * 32 + (l >> 4) * 8;
        bf16x8 v = *(const bf16x8*)&vt[((size_t)bh * HC_ + c) * NQ + n];
        *(bf16x8*)&vp[(size_t)i * 8] = v;
    }
}

// =====================================================================
// MFMA flash attention v4: 1-wave blocks (16 queries each), packed K/V
// fragments (coalesced 1KB wave-loads, immediate-offset addressing),
// defer-max (skip rescale unless max grows by >8), cvt_pk P conversion,
// setprio around MFMA clusters. Swapped-operand softmax (lane owns one
// query), layout identical to validated R5 kernel.
// =====================================================================
__global__ __launch_bounds__(64) void attn_mfma4_k(
    const float* __restrict__ q, const ushort* __restrict__ kp,
    const ushort* __restrict__ vp, ushort* __restrict__ ohl)
{
    __shared__ __align__(16) ushort Pl[1024];

    const int mt = blockIdx.x;          // 0..63: 16-query tile
    const int bh = blockIdx.y;          // 0..95
    const int b = bh / NH, h = bh % NH;
    const int lane = threadIdx.x;
    const int c15 = lane & 15;
    const int lg = lane >> 4;
    const int sw = (c15 & 7) << 3;

    const float scale = 0.17677669529663687f;

    bf16x8 qf;
    {
        const float* qp = &q[((size_t)b * NQ + mt * 16 + c15) * NC_ + h * HC_ + lg * 8];
        float tmp[8];
        *(float4*)&tmp[0] = *(const float4*)qp;
        *(float4*)&tmp[4] = *(const float4*)(qp + 4);
#pragma unroll
        for (int i = 0; i < 8; ++i) tmp[i] *= scale;
        qf = pack8(tmp);
    }

    f32x4 oacc[2];
    oacc[0] = (f32x4){0.f, 0.f, 0.f, 0.f};
    oacc[1] = (f32x4){0.f, 0.f, 0.f, 0.f};
    float m_i = -INFINITY, l_i = 0.f;

    const ushort* kpb = kp + (size_t)bh * 32768 + lane * 8;
    const ushort* vpb = vp + (size_t)bh * 32768 + lane * 8;
    const f32x4 z = (f32x4){0.f, 0.f, 0.f, 0.f};

    for (int t = 0; t < 16; ++t) {
        const ushort* kt0 = kpb + t * 2048;
        const ushort* vt0 = vpb + t * 2048;
        bf16x8 kf0 = *(const bf16x8*)(kt0);
        bf16x8 kf1 = *(const bf16x8*)(kt0 + 512);
        bf16x8 kf2 = *(const bf16x8*)(kt0 + 1024);
        bf16x8 kf3 = *(const bf16x8*)(kt0 + 1536);
        bf16x8 vf00 = *(const bf16x8*)(vt0);          // kblk0, ct0
        bf16x8 vf01 = *(const bf16x8*)(vt0 + 512);    // kblk0, ct1
        bf16x8 vf10 = *(const bf16x8*)(vt0 + 1024);   // kblk1, ct0
        bf16x8 vf11 = *(const bf16x8*)(vt0 + 1536);   // kblk1, ct1

        __builtin_amdgcn_s_setprio(1);
        f32x4 sacc[4];
        sacc[0] = __builtin_amdgcn_mfma_f32_16x16x32_bf16(kf0, qf, z, 0, 0, 0);
        sacc[1] = __builtin_amdgcn_mfma_f32_16x16x32_bf16(kf1, qf, z, 0, 0, 0);
        sacc[2] = __builtin_amdgcn_mfma_f32_16x16x32_bf16(kf2, qf, z, 0, 0, 0);
        sacc[3] = __builtin_amdgcn_mfma_f32_16x16x32_bf16(kf3, qf, z, 0, 0, 0);
        __builtin_amdgcn_s_setprio(0);

        // in-lane max over this lane's 16 keys + cross-lg combine
        float mx = sacc[0][0];
#pragma unroll
        for (int kt = 0; kt < 4; ++kt)
#pragma unroll
            for (int r = 0; r < 4; ++r) mx = fmaxf(mx, sacc[kt][r]);
        mx = fmaxf(mx, __shfl_xor(mx, 16, 64));
        mx = fmaxf(mx, __shfl_xor(mx, 32, 64));

        // defer-max: rescale only if max grew by >8 (first tile always)
        if (__any(mx > m_i + 8.f)) {
            float mn = fmaxf(m_i, mx);
            float al = __expf(m_i - mn);
            m_i = mn;
            l_i *= al;
#pragma unroll
            for (int r = 0; r < 4; ++r) {
                float ar = __shfl(al, lg * 4 + r, 64);
                oacc[0][r] *= ar;
                oacc[1][r] *= ar;
            }
        }

        float rs = 0.f;
#pragma unroll
        for (int kt = 0; kt < 4; ++kt) {
            float p0 = __expf(sacc[kt][0] - m_i);
            float p1 = __expf(sacc[kt][1] - m_i);
            float p2 = __expf(sacc[kt][2] - m_i);
            float p3 = __expf(sacc[kt][3] - m_i);
            rs += (p0 + p1) + (p2 + p3);
            ushort2 a2 = pk2(p0, p1);
            ushort2 b2 = pk2(p2, p3);
            ushort4 pk4;
            pk4.x = a2.x; pk4.y = a2.y; pk4.z = b2.x; pk4.w = b2.y;
            *(ushort4*)&Pl[c15 * 64 + ((kt * 16 + lg * 4) ^ sw)] = pk4;
        }
        rs += __shfl_xor(rs, 16, 64);
        rs += __shfl_xor(rs, 32, 64);
        l_i += rs;

        __builtin_amdgcn_s_setprio(1);
        {
            bf16x8 pf0 = *(bf16x8*)&Pl[c15 * 64 + ((lg * 8) ^ sw)];
            oacc[0] = __builtin_amdgcn_mfma_f32_16x16x32_bf16(pf0, vf00, oacc[0], 0, 0, 0);
            oacc[1] = __builtin_amdgcn_mfma_f32_16x16x32_bf16(pf0, vf01, oacc[1], 0, 0, 0);
            bf16x8 pf1 = *(bf16x8*)&Pl[c15 * 64 + ((32 + lg * 8) ^ sw)];
            oacc[0] = __builtin_amdgcn_mfma_f32_16x16x32_bf16(pf1, vf10, oacc[0], 0, 0, 0);
            oacc[1] = __builtin_amdgcn_mfma_f32_16x16x32_bf16(pf1, vf11, oacc[1], 0, 0, 0);
        }
        __builtin_amdgcn_s_setprio(0);
    }

    float linv = 1.f / l_i;
#pragma unroll
    for (int r = 0; r < 4; ++r) {
        const float lir = __shfl(linv, lg * 4 + r, 64);
        const size_t row = (size_t)b * NQ + mt * 16 + lg * 4 + r;
#pragma unroll
        for (int ct = 0; ct < 2; ++ct) {
            const float val = oacc[ct][r] * lir;
            const ushort hh = f2bf(val);
            const size_t idx = row * NC_ + h * HC_ + ct * 16 + c15;
            ohl[idx] = hh;
            ohl[NPOS_ELEMS + idx] = f2bf(val - bf2f(hh));
        }
    }
}

// =====================================================================
// Launch. ws floats (NPOS = 3,145,728):
// slot0: q fp32 | slot1: t fp32, later kp (bf16 frags) | slot2: xs hi/lo,
// later attn-out hi/lo | slot3: x hi/lo (early), later kb16 | vb16->vp
// slot4: vt | wtc | wtsq | slot5 (5*NPOS): warp coords
// =====================================================================
extern "C" void kernel_launch(void* const* d_in, const int* in_sizes, int n_in,
                              void* d_out, int out_size, void* d_ws, size_t ws_size,
                              hipStream_t stream)
{
    const float* x      = (const float*)d_in[0];
    const float* w_q    = (const float*)d_in[1];
    const float* b_q    = (const float*)d_in[2];
    const float* w_off0 = (const float*)d_in[3];
    const float* b_off0 = (const float*)d_in[4];
    const float* ln_g   = (const float*)d_in[5];
    const float* ln_b   = (const float*)d_in[6];
    const float* w_offp = (const float*)d_in[7];
    const float* w_k    = (const float*)d_in[8];
    const float* b_k    = (const float*)d_in[9];
    const float* w_v    = (const float*)d_in[10];
    const float* b_v    = (const float*)d_in[11];
    const float* w_o    = (const float*)d_in[12];
    const float* b_o    = (const float*)d_in[13];

    float* ws = (float*)d_ws;
    float*  q     = ws;
    float*  t     = ws + (size_t)NPOS_ELEMS;
    ushort* kpak  = (ushort*)t;                              // after ln_gelu, t is dead
    ushort* xs_hl = (ushort*)(ws + (size_t)2 * NPOS_ELEMS);  // also attn-out hi/lo
    ushort* xhl   = (ushort*)(ws + (size_t)3 * NPOS_ELEMS);  // dead after gemm q
    ushort* kb16  = (ushort*)(ws + (size_t)3 * NPOS_ELEMS);
    ushort* vb16  = kb16 + NPOS_ELEMS;
    ushort* vpak  = vb16;                                    // vb16 dead after vtrans
    ushort* vt    = (ushort*)(ws + (size_t)4 * NPOS_ELEMS);
    ushort* wtc   = vt + NPOS_ELEMS;
    ushort* wtsq  = wtc + 2 * WT_ELEMS;
    float*  wp    = ws + (size_t)5 * NPOS_ELEMS;

    ushort* wtq = wtsq;
    ushort* wtk = wtsq + 2 * WSQ;
    ushort* wtv = wtsq + 4 * WSQ;
    ushort* wto = wtsq + 6 * WSQ;

    const int M = BB * NQ;   // 8192

    wconv_t_k<<<108, 256, 0, stream>>>(w_off0, wtc);
    wsplit_k<<<dim3(6, 6, 4), 256, 0, stream>>>(w_q, w_k, w_v, w_o, wtsq);
    split_k<<<NPOS_ELEMS / 1024, 256, 0, stream>>>(x, xhl, NPOS_ELEMS);
    gemm_sq_k<<<dim3(M / 64, 6), 256, 0, stream>>>(xhl, wtq, b_q, q, M);
    conv_mfma_k<<<BB * 8 * NG, 256, 0, stream>>>(q, wtc, b_off0, t);
    ln_gelu_off_k<<<M, 384, 0, stream>>>(t, ln_g, ln_b, w_offp, wp);
    sample_kk<<<(BB * NG * NQ * 16) / 256, 256, 0, stream>>>(x, wp, xs_hl);
    gemm_kv_k<<<dim3(M / 64, 6), 256, 0, stream>>>(xs_hl, wtk, wtv, b_k, b_v, kb16, vb16, M);
    vtrans_k<<<BB * NH * 16, 256, 0, stream>>>(vb16, vt);
    kvpack_k<<<(96 * 4096) / 256, 256, 0, stream>>>(kb16, vt, kpak, vpak);
    attn_mfma4_k<<<dim3(64, 96), 64, 0, stream>>>(q, kpak, vpak, xs_hl);
    gemm_sq_k<<<dim3(M / 64, 6), 256, 0, stream>>>(xs_hl, wto, b_o, (float*)d_out, M);
}